// Round 1
// baseline (512.482 us; speedup 1.0000x reference)
//
#include <hip/hip_runtime.h>
#include <cstdint>
#include <cstddef>

// ---------------------------------------------------------------------------
// GCN: 3 layers, shared graph. Strategy:
//   1. Build degree + CSR-by-dst once (count, scan, atomic fill).
//   2. Per layer: GEMM (fp32, vector ALU) then CSR gather-aggregate.
//   3. Layer 3 reordered: Agg(h)@W3 (linearity), fused GEMM+bias+log_softmax.
// ---------------------------------------------------------------------------

__global__ void count_kernel(const int* __restrict__ ei, int E, int* __restrict__ cnt) {
    int i = blockIdx.x * blockDim.x + threadIdx.x;
    int stride = gridDim.x * blockDim.x;
    for (int e = i; e < E; e += stride) {
        atomicAdd(&cnt[ei[E + e]], 1);
    }
}

__global__ void dis_kernel(const int* __restrict__ cnt, float* __restrict__ dis, int n) {
    int v = blockIdx.x * blockDim.x + threadIdx.x;
    if (v < n) dis[v] = rsqrtf((float)(cnt[v] + 1));  // +1 self-loop; deg>=1 always
}

// single-block exclusive scan over cnt[n] -> row_ptr[n+1]
__global__ void scan_kernel(const int* __restrict__ cnt, int* __restrict__ row_ptr, int n) {
    __shared__ int sums[1024];
    int tid = threadIdx.x;
    int chunk = (n + 1023) >> 10;
    int beg = tid * chunk;
    int end = min(beg + chunk, n);
    int s = 0;
    for (int i = beg; i < end; ++i) s += cnt[i];
    sums[tid] = s;
    __syncthreads();
    for (int d = 1; d < 1024; d <<= 1) {
        int t = (tid >= d) ? sums[tid - d] : 0;
        __syncthreads();
        sums[tid] += t;
        __syncthreads();
    }
    int off = sums[tid] - s;  // exclusive prefix
    for (int i = beg; i < end; ++i) { row_ptr[i] = off; off += cnt[i]; }
    if (tid == 1023) row_ptr[n] = sums[1023];
}

__global__ void fill_kernel(const int* __restrict__ ei, int E,
                            const int* __restrict__ row_ptr, int* __restrict__ fillc,
                            const float* __restrict__ dis, int2* __restrict__ esort) {
    int i = blockIdx.x * blockDim.x + threadIdx.x;
    int stride = gridDim.x * blockDim.x;
    for (int e = i; e < E; e += stride) {
        int s = ei[e];
        int d = ei[E + e];
        int pos = row_ptr[d] + atomicAdd(&fillc[d], 1);
        float nm = dis[s] * dis[d];
        esort[pos] = make_int2(s, __float_as_int(nm));
    }
}

// out[n][128] = A[n][128] @ W[128][128].  32-row LDS tile, 4x4 reg blocking.
__global__ __launch_bounds__(256) void gemm128_kernel(const float* __restrict__ A,
        const float* __restrict__ W, float* __restrict__ out, int n) {
    __shared__ float xs[32][128];
    int tid = threadIdx.x;
    int row0 = blockIdx.x * 32;
#pragma unroll
    for (int i = 0; i < 4; ++i) {
        int idx = tid + i * 256;          // 0..1023 -> (row, k-quad)
        int r = idx >> 5;
        int k4 = (idx & 31) * 4;
        float4 v = make_float4(0.f, 0.f, 0.f, 0.f);
        if (row0 + r < n)
            v = *reinterpret_cast<const float4*>(A + (size_t)(row0 + r) * 128 + k4);
        *reinterpret_cast<float4*>(&xs[r][k4]) = v;
    }
    __syncthreads();
    int tx = (tid & 31) * 4;   // output col base
    int ty = (tid >> 5) * 4;   // output row base (within tile)
    float acc[4][4] = {};
#pragma unroll 4
    for (int k = 0; k < 128; ++k) {
        float4 w = *reinterpret_cast<const float4*>(W + k * 128 + tx);
#pragma unroll
        for (int i = 0; i < 4; ++i) {
            float a = xs[ty + i][k];
            acc[i][0] += a * w.x; acc[i][1] += a * w.y;
            acc[i][2] += a * w.z; acc[i][3] += a * w.w;
        }
    }
#pragma unroll
    for (int i = 0; i < 4; ++i) {
        int r = row0 + ty + i;
        if (r < n) {
            float4 o = make_float4(acc[i][0], acc[i][1], acc[i][2], acc[i][3]);
            *reinterpret_cast<float4*>(out + (size_t)r * 128 + tx) = o;
        }
    }
}

// CSR aggregation: one wave per node, lane owns 2 feature dims.
// mode: 0 = plain, 1 = +bias, 2 = +bias+relu
__global__ __launch_bounds__(256) void agg_kernel(const float* __restrict__ xw,
        const int* __restrict__ row_ptr, const int2* __restrict__ esort,
        const float* __restrict__ dis, const float* __restrict__ bias,
        float* __restrict__ out, int n, int mode) {
    int v = (int)((blockIdx.x * blockDim.x + threadIdx.x) >> 6);
    int lane = threadIdx.x & 63;
    if (v >= n) return;
    float2 acc = make_float2(0.f, 0.f);
    int beg = row_ptr[v], end = row_ptr[v + 1];
    for (int e = beg; e < end; ++e) {
        int2 ed = esort[e];                       // wave-uniform 8B load
        float w = __int_as_float(ed.y);
        float2 xv = *reinterpret_cast<const float2*>(xw + (size_t)ed.x * 128 + lane * 2);
        acc.x += w * xv.x;
        acc.y += w * xv.y;
    }
    float dv = dis[v];
    float wv = dv * dv;                            // self-loop norm
    float2 xv = *reinterpret_cast<const float2*>(xw + (size_t)v * 128 + lane * 2);
    acc.x += wv * xv.x;
    acc.y += wv * xv.y;
    if (mode >= 1) { acc.x += bias[lane * 2]; acc.y += bias[lane * 2 + 1]; }
    if (mode == 2) { acc.x = fmaxf(acc.x, 0.f); acc.y = fmaxf(acc.y, 0.f); }
    *reinterpret_cast<float2*>(out + (size_t)v * 128 + lane * 2) = acc;
}

// out[r] = log_softmax(h[r] @ W3 + b3), one thread per row, W3 in LDS.
__global__ __launch_bounds__(256) void out_kernel(const float* __restrict__ h,
        const float* __restrict__ W3, const float* __restrict__ b3,
        float* __restrict__ out, int n) {
    __shared__ float w[1280];
    for (int i = threadIdx.x; i < 1280; i += 256) w[i] = W3[i];
    __syncthreads();
    int r = blockIdx.x * blockDim.x + threadIdx.x;
    if (r >= n) return;
    float acc[10];
#pragma unroll
    for (int c = 0; c < 10; ++c) acc[c] = b3[c];
    const float4* hp = reinterpret_cast<const float4*>(h + (size_t)r * 128);
#pragma unroll 8
    for (int k4 = 0; k4 < 32; ++k4) {
        float4 a = hp[k4];
#pragma unroll
        for (int c = 0; c < 10; ++c) {
            acc[c] += a.x * w[(k4 * 4 + 0) * 10 + c] + a.y * w[(k4 * 4 + 1) * 10 + c]
                    + a.z * w[(k4 * 4 + 2) * 10 + c] + a.w * w[(k4 * 4 + 3) * 10 + c];
        }
    }
    float m = acc[0];
#pragma unroll
    for (int c = 1; c < 10; ++c) m = fmaxf(m, acc[c]);
    float ssum = 0.f;
#pragma unroll
    for (int c = 0; c < 10; ++c) ssum += __expf(acc[c] - m);
    float ls = __logf(ssum);
#pragma unroll
    for (int c = 0; c < 10; ++c) out[(size_t)r * 10 + c] = acc[c] - m - ls;
}

extern "C" void kernel_launch(void* const* d_in, const int* in_sizes, int n_in,
                              void* d_out, int out_size, void* d_ws, size_t ws_size,
                              hipStream_t stream) {
    const float* x  = (const float*)d_in[0];
    const int*   ei = (const int*)d_in[1];   // [2][E], harness stores integers as int32
    const float* W1 = (const float*)d_in[2];
    const float* b1 = (const float*)d_in[3];
    const float* W2 = (const float*)d_in[4];
    const float* b2 = (const float*)d_in[5];
    const float* W3 = (const float*)d_in[6];
    const float* b3 = (const float*)d_in[7];
    int N = in_sizes[0] / 128;
    int E = in_sizes[1] / 2;

    char* ws = (char*)d_ws;
    size_t off = 0;
    auto alloc = [&](size_t bytes) -> char* {
        char* p = ws + off;
        off = (off + bytes + 255) & ~(size_t)255;
        return p;
    };
    int*   cnt     = (int*)alloc((size_t)N * 4);
    int*   fillc   = (int*)alloc((size_t)N * 4);
    int*   row_ptr = (int*)alloc(((size_t)N + 1) * 4);
    float* dis     = (float*)alloc((size_t)N * 4);
    int2*  esort   = (int2*)alloc((size_t)E * 8);
    float* bufA    = (float*)alloc((size_t)N * 128 * 4);
    float* bufB    = (float*)alloc((size_t)N * 128 * 4);

    hipMemsetAsync(cnt, 0, (size_t)N * 4, stream);
    hipMemsetAsync(fillc, 0, (size_t)N * 4, stream);

    // --- graph preprocessing (shared by all 3 layers) ---
    count_kernel<<<2048, 256, 0, stream>>>(ei, E, cnt);
    dis_kernel<<<(N + 255) / 256, 256, 0, stream>>>(cnt, dis, N);
    scan_kernel<<<1, 1024, 0, stream>>>(cnt, row_ptr, N);
    fill_kernel<<<2048, 256, 0, stream>>>(ei, E, row_ptr, fillc, dis, esort);

    // --- layer 1: relu(Agg(x@W1) + b1) ---
    gemm128_kernel<<<(N + 31) / 32, 256, 0, stream>>>(x, W1, bufA, N);
    agg_kernel<<<(N + 3) / 4, 256, 0, stream>>>(bufA, row_ptr, esort, dis, b1, bufB, N, 2);
    // --- layer 2: Agg(h1@W2) + b2 ---
    gemm128_kernel<<<(N + 31) / 32, 256, 0, stream>>>(bufB, W2, bufA, N);
    agg_kernel<<<(N + 3) / 4, 256, 0, stream>>>(bufA, row_ptr, esort, dis, b2, bufB, N, 1);
    // --- layer 3 (reordered): log_softmax(Agg(h2)@W3 + b3) ---
    agg_kernel<<<(N + 3) / 4, 256, 0, stream>>>(bufB, row_ptr, esort, dis, nullptr, bufA, N, 0);
    out_kernel<<<(N + 255) / 256, 256, 0, stream>>>(bufA, W3, b3, (float*)d_out, N);
}

// Round 2
// 406.873 us; speedup vs baseline: 1.2596x; 1.2596x over previous
//
#include <hip/hip_runtime.h>
#include <cstdint>
#include <cstddef>

// ---------------------------------------------------------------------------
// GCN: 3 layers, shared graph.
//   - Graph preprocessing once: degree, D^-1/2, CSR-by-dst (count/scan/fill).
//   - Features between stages stored as packed bf16x2 (halves gather bytes;
//     the agg kernels are L2-fill-traffic-bound on a 25.6MB random gather).
//   - Accumulation always f32. Final agg output + log_softmax stay f32.
//   - Layer 3 reordered via linearity: log_softmax(Agg(h2) @ W3 + b3).
// ---------------------------------------------------------------------------

typedef unsigned int uint;

__device__ __forceinline__ float bf_lo(uint v) { return __uint_as_float(v << 16); }
__device__ __forceinline__ float bf_hi(uint v) { return __uint_as_float(v & 0xffff0000u); }
__device__ __forceinline__ uint pack_bf2(float a, float b) {
    uint ua = __float_as_uint(a);
    uint ub = __float_as_uint(b);
    ua = (ua + 0x7fffu + ((ua >> 16) & 1u)) >> 16;          // RNE
    ub = (ub + 0x7fffu + ((ub >> 16) & 1u)) >> 16;
    return ua | (ub << 16);
}

__global__ void count_kernel(const int* __restrict__ ei, int E, int* __restrict__ cnt) {
    int i = blockIdx.x * blockDim.x + threadIdx.x;
    int stride = gridDim.x * blockDim.x;
    for (int e = i; e < E; e += stride) atomicAdd(&cnt[ei[E + e]], 1);
}

__global__ void dis_kernel(const int* __restrict__ cnt, float* __restrict__ dis, int n) {
    int v = blockIdx.x * blockDim.x + threadIdx.x;
    if (v < n) dis[v] = rsqrtf((float)(cnt[v] + 1));  // +1 self-loop; deg>=1 always
}

// single-block exclusive scan over cnt[n] -> row_ptr[n+1]
__global__ void scan_kernel(const int* __restrict__ cnt, int* __restrict__ row_ptr, int n) {
    __shared__ int sums[1024];
    int tid = threadIdx.x;
    int chunk = (n + 1023) >> 10;
    int beg = tid * chunk;
    int end = min(beg + chunk, n);
    int s = 0;
    for (int i = beg; i < end; ++i) s += cnt[i];
    sums[tid] = s;
    __syncthreads();
    for (int d = 1; d < 1024; d <<= 1) {
        int t = (tid >= d) ? sums[tid - d] : 0;
        __syncthreads();
        sums[tid] += t;
        __syncthreads();
    }
    int off = sums[tid] - s;  // exclusive prefix
    for (int i = beg; i < end; ++i) { row_ptr[i] = off; off += cnt[i]; }
    if (tid == 1023) row_ptr[n] = sums[1023];
}

__global__ void fill_kernel(const int* __restrict__ ei, int E,
                            const int* __restrict__ row_ptr, int* __restrict__ fillc,
                            const float* __restrict__ dis, int2* __restrict__ esort) {
    int i = blockIdx.x * blockDim.x + threadIdx.x;
    int stride = gridDim.x * blockDim.x;
    for (int e = i; e < E; e += stride) {
        int s = ei[e];
        int d = ei[E + e];
        int pos = row_ptr[d] + atomicAdd(&fillc[d], 1);
        float nm = dis[s] * dis[d];
        esort[pos] = make_int2(s, __float_as_int(nm));
    }
}

// out[n][128](bf16x2 packed) = A[n][128] @ W[128][128].  TA = float or ushort(bf16).
template <typename TA>
__global__ __launch_bounds__(256) void gemm128_kernel(const TA* __restrict__ A,
        const float* __restrict__ W, uint* __restrict__ out, int n) {
    __shared__ float xs[32][128];
    int tid = threadIdx.x;
    int row0 = blockIdx.x * 32;
    if constexpr (sizeof(TA) == 4) {
#pragma unroll
        for (int i = 0; i < 4; ++i) {
            int idx = tid + i * 256;          // 1024 float4-groups? no: (row, k-quad)
            int r = idx >> 5;
            int k4 = (idx & 31) * 4;
            float4 v = make_float4(0.f, 0.f, 0.f, 0.f);
            if (row0 + r < n)
                v = *reinterpret_cast<const float4*>((const float*)A + (size_t)(row0 + r) * 128 + k4);
            *reinterpret_cast<float4*>(&xs[r][k4]) = v;
        }
    } else {
#pragma unroll
        for (int i = 0; i < 2; ++i) {
            int idx = tid + i * 256;          // 512 groups of 8 bf16
            int r = idx >> 4;
            int g8 = (idx & 15) * 8;
            uint4 v = make_uint4(0u, 0u, 0u, 0u);
            if (row0 + r < n)
                v = *reinterpret_cast<const uint4*>((const unsigned short*)A + (size_t)(row0 + r) * 128 + g8);
            xs[r][g8 + 0] = bf_lo(v.x); xs[r][g8 + 1] = bf_hi(v.x);
            xs[r][g8 + 2] = bf_lo(v.y); xs[r][g8 + 3] = bf_hi(v.y);
            xs[r][g8 + 4] = bf_lo(v.z); xs[r][g8 + 5] = bf_hi(v.z);
            xs[r][g8 + 6] = bf_lo(v.w); xs[r][g8 + 7] = bf_hi(v.w);
        }
    }
    __syncthreads();
    int tx = (tid & 31) * 4;   // output col base
    int ty = (tid >> 5) * 4;   // output row base (within tile)
    float acc[4][4] = {};
#pragma unroll 4
    for (int k = 0; k < 128; ++k) {
        float4 w = *reinterpret_cast<const float4*>(W + k * 128 + tx);
#pragma unroll
        for (int i = 0; i < 4; ++i) {
            float a = xs[ty + i][k];
            acc[i][0] += a * w.x; acc[i][1] += a * w.y;
            acc[i][2] += a * w.z; acc[i][3] += a * w.w;
        }
    }
#pragma unroll
    for (int i = 0; i < 4; ++i) {
        int r = row0 + ty + i;
        if (r < n) {
            uint2 o = make_uint2(pack_bf2(acc[i][0], acc[i][1]), pack_bf2(acc[i][2], acc[i][3]));
            *reinterpret_cast<uint2*>(out + (size_t)r * 64 + tx / 2) = o;
        }
    }
}

// CSR aggregation over packed-bf16 features. One wave per node, lane owns 2 dims.
// MODE: 0 = plain, 1 = +bias, 2 = +bias+relu.  OUTBF: write bf16x2 or f32.
template <int MODE, bool OUTBF>
__global__ __launch_bounds__(256) void agg_kernel(const uint* __restrict__ xw,
        const int* __restrict__ row_ptr, const int2* __restrict__ esort,
        const float* __restrict__ dis, const float* __restrict__ bias,
        void* __restrict__ out, int n) {
    int v = (int)((blockIdx.x * blockDim.x + threadIdx.x) >> 6);
    int lane = threadIdx.x & 63;
    if (v >= n) return;
    float ax = 0.f, ay = 0.f;
    int beg = row_ptr[v], end = row_ptr[v + 1];
    int e = beg;
    for (; e + 1 < end; e += 2) {
        int2 e0 = esort[e];
        int2 e1 = esort[e + 1];
        uint v0 = xw[(size_t)e0.x * 64 + lane];
        uint v1 = xw[(size_t)e1.x * 64 + lane];
        float w0 = __int_as_float(e0.y);
        float w1 = __int_as_float(e1.y);
        ax += w0 * bf_lo(v0); ay += w0 * bf_hi(v0);
        ax += w1 * bf_lo(v1); ay += w1 * bf_hi(v1);
    }
    if (e < end) {
        int2 e0 = esort[e];
        uint v0 = xw[(size_t)e0.x * 64 + lane];
        float w0 = __int_as_float(e0.y);
        ax += w0 * bf_lo(v0); ay += w0 * bf_hi(v0);
    }
    float dv = dis[v];
    float wv = dv * dv;                            // self-loop norm
    uint vs = xw[(size_t)v * 64 + lane];
    ax += wv * bf_lo(vs); ay += wv * bf_hi(vs);
    if (MODE >= 1) { ax += bias[lane * 2]; ay += bias[lane * 2 + 1]; }
    if (MODE == 2) { ax = fmaxf(ax, 0.f); ay = fmaxf(ay, 0.f); }
    if (OUTBF) {
        ((uint*)out)[(size_t)v * 64 + lane] = pack_bf2(ax, ay);
    } else {
        ((float2*)out)[(size_t)v * 64 + lane] = make_float2(ax, ay);
    }
}

// out[r] = log_softmax(h[r] @ W3 + b3), one thread per row, W3 in LDS.
__global__ __launch_bounds__(256) void out_kernel(const float* __restrict__ h,
        const float* __restrict__ W3, const float* __restrict__ b3,
        float* __restrict__ out, int n) {
    __shared__ float w[1280];
    for (int i = threadIdx.x; i < 1280; i += 256) w[i] = W3[i];
    __syncthreads();
    int r = blockIdx.x * blockDim.x + threadIdx.x;
    if (r >= n) return;
    float acc[10];
#pragma unroll
    for (int c = 0; c < 10; ++c) acc[c] = b3[c];
    const float4* hp = reinterpret_cast<const float4*>(h + (size_t)r * 128);
#pragma unroll 8
    for (int k4 = 0; k4 < 32; ++k4) {
        float4 a = hp[k4];
#pragma unroll
        for (int c = 0; c < 10; ++c) {
            acc[c] += a.x * w[(k4 * 4 + 0) * 10 + c] + a.y * w[(k4 * 4 + 1) * 10 + c]
                    + a.z * w[(k4 * 4 + 2) * 10 + c] + a.w * w[(k4 * 4 + 3) * 10 + c];
        }
    }
    float m = acc[0];
#pragma unroll
    for (int c = 1; c < 10; ++c) m = fmaxf(m, acc[c]);
    float ssum = 0.f;
#pragma unroll
    for (int c = 0; c < 10; ++c) ssum += __expf(acc[c] - m);
    float ls = __logf(ssum);
#pragma unroll
    for (int c = 0; c < 10; ++c) out[(size_t)r * 10 + c] = acc[c] - m - ls;
}

extern "C" void kernel_launch(void* const* d_in, const int* in_sizes, int n_in,
                              void* d_out, int out_size, void* d_ws, size_t ws_size,
                              hipStream_t stream) {
    const float* x  = (const float*)d_in[0];
    const int*   ei = (const int*)d_in[1];   // [2][E] int32
    const float* W1 = (const float*)d_in[2];
    const float* b1 = (const float*)d_in[3];
    const float* W2 = (const float*)d_in[4];
    const float* b2 = (const float*)d_in[5];
    const float* W3 = (const float*)d_in[6];
    const float* b3 = (const float*)d_in[7];
    int N = in_sizes[0] / 128;
    int E = in_sizes[1] / 2;

    char* ws = (char*)d_ws;
    size_t off = 0;
    auto alloc = [&](size_t bytes) -> char* {
        char* p = ws + off;
        off = (off + bytes + 255) & ~(size_t)255;
        return p;
    };
    int*   cnt     = (int*)alloc((size_t)N * 4);
    int*   fillc   = (int*)alloc((size_t)N * 4);
    int*   row_ptr = (int*)alloc(((size_t)N + 1) * 4);
    float* dis     = (float*)alloc((size_t)N * 4);
    int2*  esort   = (int2*)alloc((size_t)E * 8);
    uint*  bufA    = (uint*)alloc((size_t)N * 64 * 4);   // bf16x2 packed [N][64]
    uint*  bufB    = (uint*)alloc((size_t)N * 64 * 4);   // bf16x2 packed [N][64]
    float* bufC    = (float*)alloc((size_t)N * 128 * 4); // f32 final agg

    hipMemsetAsync(cnt, 0, (size_t)N * 4, stream);
    hipMemsetAsync(fillc, 0, (size_t)N * 4, stream);

    // --- graph preprocessing (shared by all 3 layers) ---
    count_kernel<<<2048, 256, 0, stream>>>(ei, E, cnt);
    dis_kernel<<<(N + 255) / 256, 256, 0, stream>>>(cnt, dis, N);
    scan_kernel<<<1, 1024, 0, stream>>>(cnt, row_ptr, N);
    fill_kernel<<<2048, 256, 0, stream>>>(ei, E, row_ptr, fillc, dis, esort);

    // --- layer 1: relu(Agg(x@W1) + b1) ---
    gemm128_kernel<float><<<(N + 31) / 32, 256, 0, stream>>>(x, W1, bufA, N);
    agg_kernel<2, true><<<(N + 3) / 4, 256, 0, stream>>>(bufA, row_ptr, esort, dis, b1, bufB, N);
    // --- layer 2: Agg(h1@W2) + b2 ---
    gemm128_kernel<unsigned short><<<(N + 31) / 32, 256, 0, stream>>>(
        (const unsigned short*)bufB, W2, bufA, N);
    agg_kernel<1, true><<<(N + 3) / 4, 256, 0, stream>>>(bufA, row_ptr, esort, dis, b2, bufB, N);
    // --- layer 3 (reordered): log_softmax(Agg(h2)@W3 + b3) ---
    agg_kernel<0, false><<<(N + 3) / 4, 256, 0, stream>>>(bufB, row_ptr, esort, dis, nullptr, bufC, N);
    out_kernel<<<(N + 255) / 256, 256, 0, stream>>>(bufC, W3, b3, (float*)d_out, N);
}

// Round 3
// 337.819 us; speedup vs baseline: 1.5170x; 1.2044x over previous
//
#include <hip/hip_runtime.h>
#include <cstdint>
#include <cstddef>

// ---------------------------------------------------------------------------
// GCN: 3 layers, shared graph.
//   - Graph preprocessing once: degree, D^-1/2, CSR-by-dst.
//     Scan is hierarchical (partial sums -> 1-wave scan -> local scan+offset);
//     the old single-block scan was 77us of pure latency (0.15% occupancy).
//   - Features between stages stored as packed bf16x2 (halves gather bytes;
//     agg kernels are L2/L3-fill-traffic-bound on a random gather).
//   - Accumulation always f32. Final agg output + log_softmax stay f32.
//   - Layer 3 reordered via linearity: log_softmax(Agg(h2) @ W3 + b3).
// ---------------------------------------------------------------------------

typedef unsigned int uint;

__device__ __forceinline__ float bf_lo(uint v) { return __uint_as_float(v << 16); }
__device__ __forceinline__ float bf_hi(uint v) { return __uint_as_float(v & 0xffff0000u); }
__device__ __forceinline__ uint pack_bf2(float a, float b) {
    uint ua = __float_as_uint(a);
    uint ub = __float_as_uint(b);
    ua = (ua + 0x7fffu + ((ua >> 16) & 1u)) >> 16;          // RNE
    ub = (ub + 0x7fffu + ((ub >> 16) & 1u)) >> 16;
    return ua | (ub << 16);
}

__global__ void count_kernel(const int* __restrict__ ei, int E, int* __restrict__ cnt) {
    int i = blockIdx.x * blockDim.x + threadIdx.x;
    int stride = gridDim.x * blockDim.x;
    for (int e = i; e < E; e += stride) atomicAdd(&cnt[ei[E + e]], 1);
}

// Pass 1: per-block (1024 elems) totals; also computes dis = rsqrt(deg+1).
__global__ __launch_bounds__(256) void scan_partial(const int* __restrict__ cnt,
        int* __restrict__ bsum, float* __restrict__ dis, int n) {
    __shared__ int red[256];
    int b = blockIdx.x, tid = threadIdx.x;
    int base = b * 1024 + tid * 4;
    int4 v = make_int4(0, 0, 0, 0);
    if (base + 4 <= n) {
        v = *reinterpret_cast<const int4*>(cnt + base);
    } else {
        if (base + 0 < n) v.x = cnt[base + 0];
        if (base + 1 < n) v.y = cnt[base + 1];
        if (base + 2 < n) v.z = cnt[base + 2];
    }
    if (base + 0 < n) dis[base + 0] = rsqrtf((float)(v.x + 1));
    if (base + 1 < n) dis[base + 1] = rsqrtf((float)(v.y + 1));
    if (base + 2 < n) dis[base + 2] = rsqrtf((float)(v.z + 1));
    if (base + 3 < n) dis[base + 3] = rsqrtf((float)(v.w + 1));
    red[tid] = v.x + v.y + v.z + v.w;
    __syncthreads();
    for (int d = 128; d > 0; d >>= 1) {
        if (tid < d) red[tid] += red[tid + d];
        __syncthreads();
    }
    if (tid == 0) bsum[b] = red[0];
}

// Pass 2: one wave scans <=64 block sums -> exclusive offsets + grand total.
__global__ void scan_bsum(const int* __restrict__ bsum, int* __restrict__ boff,
                          int* __restrict__ row_ptr, int nb, int n) {
    int tid = threadIdx.x;
    int s = (tid < nb) ? bsum[tid] : 0;
    int v = s;
    for (int d = 1; d < 64; d <<= 1) {
        int t = __shfl_up(v, d);
        if (tid >= d) v += t;
    }
    if (tid < nb) boff[tid] = v - s;    // exclusive
    if (tid == 63) row_ptr[n] = v;      // inclusive at last lane = grand total
}

// Pass 3: block-local exclusive scan + block offset -> row_ptr.
__global__ __launch_bounds__(256) void scan_final(const int* __restrict__ cnt,
        const int* __restrict__ boff, int* __restrict__ row_ptr, int n) {
    __shared__ int red[256];
    int b = blockIdx.x, tid = threadIdx.x;
    int base = b * 1024 + tid * 4;
    int4 v = make_int4(0, 0, 0, 0);
    if (base + 4 <= n) {
        v = *reinterpret_cast<const int4*>(cnt + base);
    } else {
        if (base + 0 < n) v.x = cnt[base + 0];
        if (base + 1 < n) v.y = cnt[base + 1];
        if (base + 2 < n) v.z = cnt[base + 2];
    }
    int s = v.x + v.y + v.z + v.w;
    red[tid] = s;
    __syncthreads();
    for (int d = 1; d < 256; d <<= 1) {
        int t = (tid >= d) ? red[tid - d] : 0;
        __syncthreads();
        red[tid] += t;
        __syncthreads();
    }
    int off = boff[b] + red[tid] - s;   // exclusive prefix for this thread's quad
    if (base + 0 < n) { row_ptr[base + 0] = off; off += v.x; }
    if (base + 1 < n) { row_ptr[base + 1] = off; off += v.y; }
    if (base + 2 < n) { row_ptr[base + 2] = off; off += v.z; }
    if (base + 3 < n) { row_ptr[base + 3] = off; }
}

__global__ void fill_kernel(const int* __restrict__ ei, int E,
                            const int* __restrict__ row_ptr, int* __restrict__ fillc,
                            const float* __restrict__ dis, int2* __restrict__ esort) {
    int i = blockIdx.x * blockDim.x + threadIdx.x;
    int stride = gridDim.x * blockDim.x;
    for (int e = i; e < E; e += stride) {
        int s = ei[e];
        int d = ei[E + e];
        int pos = row_ptr[d] + atomicAdd(&fillc[d], 1);
        float nm = dis[s] * dis[d];
        esort[pos] = make_int2(s, __float_as_int(nm));
    }
}

// out[n][128](bf16x2 packed) = A[n][128] @ W[128][128].  TA = float or ushort(bf16).
template <typename TA>
__global__ __launch_bounds__(256) void gemm128_kernel(const TA* __restrict__ A,
        const float* __restrict__ W, uint* __restrict__ out, int n) {
    __shared__ float xs[32][128];
    int tid = threadIdx.x;
    int row0 = blockIdx.x * 32;
    if constexpr (sizeof(TA) == 4) {
#pragma unroll
        for (int i = 0; i < 4; ++i) {
            int idx = tid + i * 256;
            int r = idx >> 5;
            int k4 = (idx & 31) * 4;
            float4 v = make_float4(0.f, 0.f, 0.f, 0.f);
            if (row0 + r < n)
                v = *reinterpret_cast<const float4*>((const float*)A + (size_t)(row0 + r) * 128 + k4);
            *reinterpret_cast<float4*>(&xs[r][k4]) = v;
        }
    } else {
#pragma unroll
        for (int i = 0; i < 2; ++i) {
            int idx = tid + i * 256;          // 512 groups of 8 bf16
            int r = idx >> 4;
            int g8 = (idx & 15) * 8;
            uint4 v = make_uint4(0u, 0u, 0u, 0u);
            if (row0 + r < n)
                v = *reinterpret_cast<const uint4*>((const unsigned short*)A + (size_t)(row0 + r) * 128 + g8);
            xs[r][g8 + 0] = bf_lo(v.x); xs[r][g8 + 1] = bf_hi(v.x);
            xs[r][g8 + 2] = bf_lo(v.y); xs[r][g8 + 3] = bf_hi(v.y);
            xs[r][g8 + 4] = bf_lo(v.z); xs[r][g8 + 5] = bf_hi(v.z);
            xs[r][g8 + 6] = bf_lo(v.w); xs[r][g8 + 7] = bf_hi(v.w);
        }
    }
    __syncthreads();
    int tx = (tid & 31) * 4;
    int ty = (tid >> 5) * 4;
    float acc[4][4] = {};
#pragma unroll 4
    for (int k = 0; k < 128; ++k) {
        float4 w = *reinterpret_cast<const float4*>(W + k * 128 + tx);
#pragma unroll
        for (int i = 0; i < 4; ++i) {
            float a = xs[ty + i][k];
            acc[i][0] += a * w.x; acc[i][1] += a * w.y;
            acc[i][2] += a * w.z; acc[i][3] += a * w.w;
        }
    }
#pragma unroll
    for (int i = 0; i < 4; ++i) {
        int r = row0 + ty + i;
        if (r < n) {
            uint2 o = make_uint2(pack_bf2(acc[i][0], acc[i][1]), pack_bf2(acc[i][2], acc[i][3]));
            *reinterpret_cast<uint2*>(out + (size_t)r * 64 + tx / 2) = o;
        }
    }
}

// CSR aggregation over packed-bf16 features. One wave per node, lane owns 2 dims.
// MODE: 0 = plain, 1 = +bias, 2 = +bias+relu.  OUTBF: write bf16x2 or f32.
template <int MODE, bool OUTBF>
__global__ __launch_bounds__(256) void agg_kernel(const uint* __restrict__ xw,
        const int* __restrict__ row_ptr, const int2* __restrict__ esort,
        const float* __restrict__ dis, const float* __restrict__ bias,
        void* __restrict__ out, int n) {
    int v = (int)((blockIdx.x * blockDim.x + threadIdx.x) >> 6);
    int lane = threadIdx.x & 63;
    if (v >= n) return;
    float ax = 0.f, ay = 0.f;
    int beg = row_ptr[v], end = row_ptr[v + 1];
    int e = beg;
    for (; e + 1 < end; e += 2) {
        int2 e0 = esort[e];
        int2 e1 = esort[e + 1];
        uint v0 = xw[(size_t)e0.x * 64 + lane];
        uint v1 = xw[(size_t)e1.x * 64 + lane];
        float w0 = __int_as_float(e0.y);
        float w1 = __int_as_float(e1.y);
        ax += w0 * bf_lo(v0); ay += w0 * bf_hi(v0);
        ax += w1 * bf_lo(v1); ay += w1 * bf_hi(v1);
    }
    if (e < end) {
        int2 e0 = esort[e];
        uint v0 = xw[(size_t)e0.x * 64 + lane];
        float w0 = __int_as_float(e0.y);
        ax += w0 * bf_lo(v0); ay += w0 * bf_hi(v0);
    }
    float dv = dis[v];
    float wv = dv * dv;                            // self-loop norm
    uint vs = xw[(size_t)v * 64 + lane];
    ax += wv * bf_lo(vs); ay += wv * bf_hi(vs);
    if (MODE >= 1) { ax += bias[lane * 2]; ay += bias[lane * 2 + 1]; }
    if (MODE == 2) { ax = fmaxf(ax, 0.f); ay = fmaxf(ay, 0.f); }
    if (OUTBF) {
        ((uint*)out)[(size_t)v * 64 + lane] = pack_bf2(ax, ay);
    } else {
        ((float2*)out)[(size_t)v * 64 + lane] = make_float2(ax, ay);
    }
}

// out[r] = log_softmax(h[r] @ W3 + b3), one thread per row, W3 in LDS.
__global__ __launch_bounds__(256) void out_kernel(const float* __restrict__ h,
        const float* __restrict__ W3, const float* __restrict__ b3,
        float* __restrict__ out, int n) {
    __shared__ float w[1280];
    for (int i = threadIdx.x; i < 1280; i += 256) w[i] = W3[i];
    __syncthreads();
    int r = blockIdx.x * blockDim.x + threadIdx.x;
    if (r >= n) return;
    float acc[10];
#pragma unroll
    for (int c = 0; c < 10; ++c) acc[c] = b3[c];
    const float4* hp = reinterpret_cast<const float4*>(h + (size_t)r * 128);
#pragma unroll 8
    for (int k4 = 0; k4 < 32; ++k4) {
        float4 a = hp[k4];
#pragma unroll
        for (int c = 0; c < 10; ++c) {
            acc[c] += a.x * w[(k4 * 4 + 0) * 10 + c] + a.y * w[(k4 * 4 + 1) * 10 + c]
                    + a.z * w[(k4 * 4 + 2) * 10 + c] + a.w * w[(k4 * 4 + 3) * 10 + c];
        }
    }
    float m = acc[0];
#pragma unroll
    for (int c = 1; c < 10; ++c) m = fmaxf(m, acc[c]);
    float ssum = 0.f;
#pragma unroll
    for (int c = 0; c < 10; ++c) ssum += __expf(acc[c] - m);
    float ls = __logf(ssum);
#pragma unroll
    for (int c = 0; c < 10; ++c) out[(size_t)r * 10 + c] = acc[c] - m - ls;
}

extern "C" void kernel_launch(void* const* d_in, const int* in_sizes, int n_in,
                              void* d_out, int out_size, void* d_ws, size_t ws_size,
                              hipStream_t stream) {
    const float* x  = (const float*)d_in[0];
    const int*   ei = (const int*)d_in[1];   // [2][E] int32
    const float* W1 = (const float*)d_in[2];
    const float* b1 = (const float*)d_in[3];
    const float* W2 = (const float*)d_in[4];
    const float* b2 = (const float*)d_in[5];
    const float* W3 = (const float*)d_in[6];
    const float* b3 = (const float*)d_in[7];
    int N = in_sizes[0] / 128;
    int E = in_sizes[1] / 2;
    int NB = (N + 1023) / 1024;   // 49 for N=50000 (must be <= 64)

    char* ws = (char*)d_ws;
    size_t off = 0;
    auto alloc = [&](size_t bytes) -> char* {
        char* p = ws + off;
        off = (off + bytes + 255) & ~(size_t)255;
        return p;
    };
    int*   cnt     = (int*)alloc((size_t)N * 4);
    int*   fillc   = (int*)alloc((size_t)N * 4);
    int*   row_ptr = (int*)alloc(((size_t)N + 1) * 4);
    float* dis     = (float*)alloc((size_t)N * 4);
    int*   bsum    = (int*)alloc(64 * 4);
    int*   boff    = (int*)alloc(64 * 4);
    int2*  esort   = (int2*)alloc((size_t)E * 8);
    uint*  bufA    = (uint*)alloc((size_t)N * 64 * 4);   // bf16x2 packed [N][64]
    uint*  bufB    = (uint*)alloc((size_t)N * 64 * 4);   // bf16x2 packed [N][64]
    float* bufC    = (float*)alloc((size_t)N * 128 * 4); // f32 final agg

    hipMemsetAsync(cnt, 0, (size_t)N * 4, stream);
    hipMemsetAsync(fillc, 0, (size_t)N * 4, stream);

    // --- graph preprocessing (shared by all 3 layers) ---
    count_kernel<<<2048, 256, 0, stream>>>(ei, E, cnt);
    scan_partial<<<NB, 256, 0, stream>>>(cnt, bsum, dis, N);
    scan_bsum<<<1, 64, 0, stream>>>(bsum, boff, row_ptr, NB, N);
    scan_final<<<NB, 256, 0, stream>>>(cnt, boff, row_ptr, N);
    fill_kernel<<<2048, 256, 0, stream>>>(ei, E, row_ptr, fillc, dis, esort);

    // --- layer 1: relu(Agg(x@W1) + b1) ---
    gemm128_kernel<float><<<(N + 31) / 32, 256, 0, stream>>>(x, W1, bufA, N);
    agg_kernel<2, true><<<(N + 3) / 4, 256, 0, stream>>>(bufA, row_ptr, esort, dis, b1, bufB, N);
    // --- layer 2: Agg(h1@W2) + b2 ---
    gemm128_kernel<unsigned short><<<(N + 31) / 32, 256, 0, stream>>>(
        (const unsigned short*)bufB, W2, bufA, N);
    agg_kernel<1, true><<<(N + 3) / 4, 256, 0, stream>>>(bufA, row_ptr, esort, dis, b2, bufB, N);
    // --- layer 3 (reordered): log_softmax(Agg(h2)@W3 + b3) ---
    agg_kernel<0, false><<<(N + 3) / 4, 256, 0, stream>>>(bufB, row_ptr, esort, dis, nullptr, bufC, N);
    out_kernel<<<(N + 255) / 256, 256, 0, stream>>>(bufC, W3, b3, (float*)d_out, N);
}

// Round 5
// 310.704 us; speedup vs baseline: 1.6494x; 1.0873x over previous
//
#include <hip/hip_runtime.h>
#include <cstdint>
#include <cstddef>

// ---------------------------------------------------------------------------
// GCN: 3 layers, shared graph.
//   - Graph preprocessing once: degree, D^-1/2, CSR-by-dst.
//     Hierarchical scan; block-sum scan folded into scan_final (redundant
//     per-block wave scan of <=64 sums beats an extra launch).
//   - Features between stages stored as packed bf16x2 (halves gather bytes).
//   - Agg kernels are LATENCY-bound (R3: 22% HBM, 28% VALU, 65% occ):
//     4-way unroll for 4 outstanding gathers/wave; nontemporal loads on the
//     streamed esort + nontemporal feature stores keep L2 for the gather
//     target (12.8 MB xw vs 4 MB/XCD L2).
//   - Layer 3 reordered via linearity AND fused with the output projection:
//     log_softmax(Agg(h2) @ W3 + b3) computed in-wave (butterfly reduce),
//     eliminating a 25 MB write + 25 MB read and one kernel.
//   - NOTE: __builtin_nontemporal_* requires scalar / clang ext_vector types,
//     NOT HIP_vector_type structs — hence the *_e typedefs below.
// ---------------------------------------------------------------------------

typedef unsigned int uint;
typedef uint  uint4e  __attribute__((ext_vector_type(4)));
typedef float float4e __attribute__((ext_vector_type(4)));
typedef uint  uint2e  __attribute__((ext_vector_type(2)));
typedef int   int2e   __attribute__((ext_vector_type(2)));

__device__ __forceinline__ float bf_lo(uint v) { return __uint_as_float(v << 16); }
__device__ __forceinline__ float bf_hi(uint v) { return __uint_as_float(v & 0xffff0000u); }
__device__ __forceinline__ uint pack_bf2(float a, float b) {
    uint ua = __float_as_uint(a);
    uint ub = __float_as_uint(b);
    ua = (ua + 0x7fffu + ((ua >> 16) & 1u)) >> 16;          // RNE
    ub = (ub + 0x7fffu + ((ub >> 16) & 1u)) >> 16;
    return ua | (ub << 16);
}

__global__ void count_kernel(const int* __restrict__ ei, int E, int* __restrict__ cnt) {
    int i = blockIdx.x * blockDim.x + threadIdx.x;
    int stride = gridDim.x * blockDim.x;
    for (int e = i; e < E; e += stride) atomicAdd(&cnt[ei[E + e]], 1);
}

// Pass 1: per-block (1024 elems) totals; also computes dis = rsqrt(deg+1).
__global__ __launch_bounds__(256) void scan_partial(const int* __restrict__ cnt,
        int* __restrict__ bsum, float* __restrict__ dis, int n) {
    __shared__ int red[256];
    int b = blockIdx.x, tid = threadIdx.x;
    int base = b * 1024 + tid * 4;
    int4 v = make_int4(0, 0, 0, 0);
    if (base + 4 <= n) {
        v = *reinterpret_cast<const int4*>(cnt + base);
    } else {
        if (base + 0 < n) v.x = cnt[base + 0];
        if (base + 1 < n) v.y = cnt[base + 1];
        if (base + 2 < n) v.z = cnt[base + 2];
    }
    if (base + 0 < n) dis[base + 0] = rsqrtf((float)(v.x + 1));
    if (base + 1 < n) dis[base + 1] = rsqrtf((float)(v.y + 1));
    if (base + 2 < n) dis[base + 2] = rsqrtf((float)(v.z + 1));
    if (base + 3 < n) dis[base + 3] = rsqrtf((float)(v.w + 1));
    red[tid] = v.x + v.y + v.z + v.w;
    __syncthreads();
    for (int d = 128; d > 0; d >>= 1) {
        if (tid < d) red[tid] += red[tid + d];
        __syncthreads();
    }
    if (tid == 0) bsum[b] = red[0];
}

// Pass 2: per-block: wave 0 redundantly scans block sums (<=64) for this
// block's offset, then block-local exclusive scan + offset -> row_ptr.
__global__ __launch_bounds__(256) void scan_final(const int* __restrict__ cnt,
        const int* __restrict__ bsum, int* __restrict__ row_ptr, int nb, int n) {
    __shared__ int red[256];
    __shared__ int sh_boff;
    int b = blockIdx.x, tid = threadIdx.x;
    if (tid < 64) {
        int s = (tid < nb) ? bsum[tid] : 0;
        int v = s;
        for (int d = 1; d < 64; d <<= 1) {
            int t = __shfl_up(v, d);
            if (tid >= d) v += t;
        }
        if (tid == b) sh_boff = v - s;                 // exclusive offset of this block
        if (b == 0 && tid == 63) row_ptr[n] = v;       // grand total
    }
    int base = b * 1024 + tid * 4;
    int4 v = make_int4(0, 0, 0, 0);
    if (base + 4 <= n) {
        v = *reinterpret_cast<const int4*>(cnt + base);
    } else {
        if (base + 0 < n) v.x = cnt[base + 0];
        if (base + 1 < n) v.y = cnt[base + 1];
        if (base + 2 < n) v.z = cnt[base + 2];
    }
    int s = v.x + v.y + v.z + v.w;
    red[tid] = s;
    __syncthreads();
    for (int d = 1; d < 256; d <<= 1) {
        int t = (tid >= d) ? red[tid - d] : 0;
        __syncthreads();
        red[tid] += t;
        __syncthreads();
    }
    int off = sh_boff + red[tid] - s;   // exclusive prefix for this thread's quad
    if (base + 0 < n) { row_ptr[base + 0] = off; off += v.x; }
    if (base + 1 < n) { row_ptr[base + 1] = off; off += v.y; }
    if (base + 2 < n) { row_ptr[base + 2] = off; off += v.z; }
    if (base + 3 < n) { row_ptr[base + 3] = off; }
}

__global__ void fill_kernel(const int* __restrict__ ei, int E,
                            const int* __restrict__ row_ptr, int* __restrict__ fillc,
                            const float* __restrict__ dis, int2e* __restrict__ esort) {
    int i = blockIdx.x * blockDim.x + threadIdx.x;
    int stride = gridDim.x * blockDim.x;
    for (int e = i; e < E; e += stride) {
        int s = ei[e];
        int d = ei[E + e];
        int pos = row_ptr[d] + atomicAdd(&fillc[d], 1);
        float nm = dis[s] * dis[d];
        int2e pkt;
        pkt.x = s;
        pkt.y = __float_as_int(nm);
        esort[pos] = pkt;
    }
}

// out[n][128](bf16x2 packed) = A[n][128] @ W[128][128].  TA = float or ushort(bf16).
template <typename TA>
__global__ __launch_bounds__(256) void gemm128_kernel(const TA* __restrict__ A,
        const float* __restrict__ W, uint* __restrict__ out, int n) {
    __shared__ float xs[32][128];
    int tid = threadIdx.x;
    int row0 = blockIdx.x * 32;
    if constexpr (sizeof(TA) == 4) {
#pragma unroll
        for (int i = 0; i < 4; ++i) {
            int idx = tid + i * 256;
            int r = idx >> 5;
            int k4 = (idx & 31) * 4;
            float4e v = {0.f, 0.f, 0.f, 0.f};
            if (row0 + r < n)
                v = __builtin_nontemporal_load(
                    reinterpret_cast<const float4e*>((const float*)A + (size_t)(row0 + r) * 128 + k4));
            *reinterpret_cast<float4e*>(&xs[r][k4]) = v;
        }
    } else {
#pragma unroll
        for (int i = 0; i < 2; ++i) {
            int idx = tid + i * 256;          // 512 groups of 8 bf16
            int r = idx >> 4;
            int g8 = (idx & 15) * 8;
            uint4e v = {0u, 0u, 0u, 0u};
            if (row0 + r < n)
                v = __builtin_nontemporal_load(
                    reinterpret_cast<const uint4e*>((const unsigned short*)A + (size_t)(row0 + r) * 128 + g8));
            xs[r][g8 + 0] = bf_lo(v.x); xs[r][g8 + 1] = bf_hi(v.x);
            xs[r][g8 + 2] = bf_lo(v.y); xs[r][g8 + 3] = bf_hi(v.y);
            xs[r][g8 + 4] = bf_lo(v.z); xs[r][g8 + 5] = bf_hi(v.z);
            xs[r][g8 + 6] = bf_lo(v.w); xs[r][g8 + 7] = bf_hi(v.w);
        }
    }
    __syncthreads();
    int tx = (tid & 31) * 4;
    int ty = (tid >> 5) * 4;
    float acc[4][4] = {};
#pragma unroll 4
    for (int k = 0; k < 128; ++k) {
        float4 w = *reinterpret_cast<const float4*>(W + k * 128 + tx);
#pragma unroll
        for (int i = 0; i < 4; ++i) {
            float a = xs[ty + i][k];
            acc[i][0] += a * w.x; acc[i][1] += a * w.y;
            acc[i][2] += a * w.z; acc[i][3] += a * w.w;
        }
    }
#pragma unroll
    for (int i = 0; i < 4; ++i) {
        int r = row0 + ty + i;
        if (r < n) {
            uint2e o = {pack_bf2(acc[i][0], acc[i][1]), pack_bf2(acc[i][2], acc[i][3])};
            __builtin_nontemporal_store(o, reinterpret_cast<uint2e*>(out + (size_t)r * 64 + tx / 2));
        }
    }
}

// Shared gather core: accumulate normalized neighbor features (f32 acc).
// 4-way unroll = 4 outstanding gathers per wave (latency hiding).
__device__ __forceinline__ void gather_accum(const uint* __restrict__ xw,
        const int2e* __restrict__ esort, const float* __restrict__ dis,
        int v, int lane, int beg, int end, float& ax, float& ay) {
    int e = beg;
    for (; e + 3 < end; e += 4) {
        int2e e0 = __builtin_nontemporal_load(esort + e);
        int2e e1 = __builtin_nontemporal_load(esort + e + 1);
        int2e e2 = __builtin_nontemporal_load(esort + e + 2);
        int2e e3 = __builtin_nontemporal_load(esort + e + 3);
        uint v0 = xw[(size_t)e0.x * 64 + lane];
        uint v1 = xw[(size_t)e1.x * 64 + lane];
        uint v2 = xw[(size_t)e2.x * 64 + lane];
        uint v3 = xw[(size_t)e3.x * 64 + lane];
        float w0 = __int_as_float(e0.y), w1 = __int_as_float(e1.y);
        float w2 = __int_as_float(e2.y), w3 = __int_as_float(e3.y);
        ax += w0 * bf_lo(v0); ay += w0 * bf_hi(v0);
        ax += w1 * bf_lo(v1); ay += w1 * bf_hi(v1);
        ax += w2 * bf_lo(v2); ay += w2 * bf_hi(v2);
        ax += w3 * bf_lo(v3); ay += w3 * bf_hi(v3);
    }
    for (; e < end; ++e) {
        int2e e0 = __builtin_nontemporal_load(esort + e);
        uint v0 = xw[(size_t)e0.x * 64 + lane];
        float w0 = __int_as_float(e0.y);
        ax += w0 * bf_lo(v0); ay += w0 * bf_hi(v0);
    }
    float dv = dis[v];
    float wv = dv * dv;                            // self-loop norm
    uint vs = xw[(size_t)v * 64 + lane];
    ax += wv * bf_lo(vs); ay += wv * bf_hi(vs);
}

// CSR aggregation -> packed bf16. MODE: 1 = +bias, 2 = +bias+relu.
template <int MODE>
__global__ __launch_bounds__(256) void agg_kernel(const uint* __restrict__ xw,
        const int* __restrict__ row_ptr, const int2e* __restrict__ esort,
        const float* __restrict__ dis, const float* __restrict__ bias,
        uint* __restrict__ out, int n) {
    int v = (int)((blockIdx.x * blockDim.x + threadIdx.x) >> 6);
    int lane = threadIdx.x & 63;
    if (v >= n) return;
    float ax = 0.f, ay = 0.f;
    gather_accum(xw, esort, dis, v, lane, row_ptr[v], row_ptr[v + 1], ax, ay);
    ax += bias[lane * 2];
    ay += bias[lane * 2 + 1];
    if (MODE == 2) { ax = fmaxf(ax, 0.f); ay = fmaxf(ay, 0.f); }
    __builtin_nontemporal_store(pack_bf2(ax, ay), out + (size_t)v * 64 + lane);
}

// Final layer fused: h = Agg(h2); out = log_softmax(h @ W3 + b3).
// Wave holds h[128] (2 dims/lane); 10 butterfly reductions for the projection.
__global__ __launch_bounds__(256) void agg_out_kernel(const uint* __restrict__ xw,
        const int* __restrict__ row_ptr, const int2e* __restrict__ esort,
        const float* __restrict__ dis, const float* __restrict__ W3,
        const float* __restrict__ b3, float* __restrict__ out, int n) {
    int v = (int)((blockIdx.x * blockDim.x + threadIdx.x) >> 6);
    int lane = threadIdx.x & 63;
    if (v >= n) return;
    float ax = 0.f, ay = 0.f;
    gather_accum(xw, esort, dis, v, lane, row_ptr[v], row_ptr[v + 1], ax, ay);
    // projection: this lane's rows of W3 (2 x 10)
    const float* w0 = W3 + (size_t)lane * 20;
    float p[10];
#pragma unroll
    for (int c = 0; c < 10; ++c) p[c] = ax * w0[c] + ay * w0[10 + c];
#pragma unroll
    for (int c = 0; c < 10; ++c) {
#pragma unroll
        for (int d = 1; d < 64; d <<= 1) p[c] += __shfl_xor(p[c], d);
    }
#pragma unroll
    for (int c = 0; c < 10; ++c) p[c] += b3[c];
    float m = p[0];
#pragma unroll
    for (int c = 1; c < 10; ++c) m = fmaxf(m, p[c]);
    float ssum = 0.f;
#pragma unroll
    for (int c = 0; c < 10; ++c) ssum += __expf(p[c] - m);
    float ls = __logf(ssum);
    if (lane < 10) out[(size_t)v * 10 + lane] = p[lane] - m - ls;
}

extern "C" void kernel_launch(void* const* d_in, const int* in_sizes, int n_in,
                              void* d_out, int out_size, void* d_ws, size_t ws_size,
                              hipStream_t stream) {
    const float* x  = (const float*)d_in[0];
    const int*   ei = (const int*)d_in[1];   // [2][E] int32
    const float* W1 = (const float*)d_in[2];
    const float* b1 = (const float*)d_in[3];
    const float* W2 = (const float*)d_in[4];
    const float* b2 = (const float*)d_in[5];
    const float* W3 = (const float*)d_in[6];
    const float* b3 = (const float*)d_in[7];
    int N = in_sizes[0] / 128;
    int E = in_sizes[1] / 2;
    int NB = (N + 1023) / 1024;   // 49 for N=50000 (must be <= 64)

    char* ws = (char*)d_ws;
    size_t off = 0;
    auto alloc = [&](size_t bytes) -> char* {
        char* p = ws + off;
        off = (off + bytes + 255) & ~(size_t)255;
        return p;
    };
    int*   cnt     = (int*)alloc((size_t)N * 4);
    int*   fillc   = (int*)alloc((size_t)N * 4);
    int*   row_ptr = (int*)alloc(((size_t)N + 1) * 4);
    float* dis     = (float*)alloc((size_t)N * 4);
    int*   bsum    = (int*)alloc(64 * 4);
    int2e* esort   = (int2e*)alloc((size_t)E * 8);
    uint*  bufA    = (uint*)alloc((size_t)N * 64 * 4);   // bf16x2 packed [N][64]
    uint*  bufB    = (uint*)alloc((size_t)N * 64 * 4);   // bf16x2 packed [N][64]

    (void)hipMemsetAsync(cnt, 0, (size_t)N * 4, stream);
    (void)hipMemsetAsync(fillc, 0, (size_t)N * 4, stream);

    // --- graph preprocessing (shared by all 3 layers) ---
    count_kernel<<<2048, 256, 0, stream>>>(ei, E, cnt);
    scan_partial<<<NB, 256, 0, stream>>>(cnt, bsum, dis, N);
    scan_final<<<NB, 256, 0, stream>>>(cnt, bsum, row_ptr, NB, N);
    fill_kernel<<<2048, 256, 0, stream>>>(ei, E, row_ptr, fillc, dis, esort);

    // --- layer 1: relu(Agg(x@W1) + b1) ---
    gemm128_kernel<float><<<(N + 31) / 32, 256, 0, stream>>>(x, W1, bufA, N);
    agg_kernel<2><<<(N + 3) / 4, 256, 0, stream>>>(bufA, row_ptr, esort, dis, b1, bufB, N);
    // --- layer 2: Agg(h1@W2) + b2 ---
    gemm128_kernel<unsigned short><<<(N + 31) / 32, 256, 0, stream>>>(
        (const unsigned short*)bufB, W2, bufA, N);
    agg_kernel<1><<<(N + 3) / 4, 256, 0, stream>>>(bufA, row_ptr, esort, dis, b2, bufB, N);
    // --- layer 3 fused: log_softmax(Agg(h2) @ W3 + b3) ---
    agg_out_kernel<<<(N + 3) / 4, 256, 0, stream>>>(bufB, row_ptr, esort, dis, W3, b3,
                                                    (float*)d_out, N);
}

// Round 6
// 246.630 us; speedup vs baseline: 2.0779x; 1.2598x over previous
//
#include <hip/hip_runtime.h>
#include <cstdint>
#include <cstddef>

// ---------------------------------------------------------------------------
// GCN: 3 layers, shared graph.
//   - Graph preprocessing once: degree, D^-1/2, CSR-by-dst, hierarchical scan.
//   - Features between stages packed bf16x2 (halves gather bytes).
//   - Agg: latency-bound random gather -> 8 outstanding loads per wave.
//     NO nontemporal hints: NT stores were evicting the gather target from
//     L2/L3 (R5: FETCH stayed ~88MB); NT esort loads thrashed reused lines.
//   - GEMMs: bf16 MFMA 16x16x32 (f32 accum). W pre-transposed to Wt[n][k]
//     bf16 once; A staged in padded LDS (stride 136 bf16 => 2-way only);
//     B-frags in registers. C/D layout: col=lane&15, row=(lane>>4)*4+reg.
//   - Layer 3 via linearity + fused projection/log_softmax (butterfly).
// ---------------------------------------------------------------------------

typedef unsigned int uint;
typedef unsigned short u16;
typedef uint  uint4e  __attribute__((ext_vector_type(4)));
typedef float float4e __attribute__((ext_vector_type(4)));
typedef uint  uint2e  __attribute__((ext_vector_type(2)));
typedef int   int2e   __attribute__((ext_vector_type(2)));
using bf16x8 = __attribute__((ext_vector_type(8))) short;
using f32x4  = __attribute__((ext_vector_type(4))) float;

__device__ __forceinline__ float bf_lo(uint v) { return __uint_as_float(v << 16); }
__device__ __forceinline__ float bf_hi(uint v) { return __uint_as_float(v & 0xffff0000u); }
__device__ __forceinline__ u16 bf16_1(float a) {
    uint ua = __float_as_uint(a);
    ua = (ua + 0x7fffu + ((ua >> 16) & 1u)) >> 16;          // RNE
    return (u16)ua;
}
__device__ __forceinline__ uint pack_bf2(float a, float b) {
    return (uint)bf16_1(a) | ((uint)bf16_1(b) << 16);
}

__global__ void count_kernel(const int* __restrict__ ei, int E, int* __restrict__ cnt) {
    int i = blockIdx.x * blockDim.x + threadIdx.x;
    int stride = gridDim.x * blockDim.x;
    for (int e = i; e < E; e += stride) atomicAdd(&cnt[ei[E + e]], 1);
}

// Pass 1: per-block (1024 elems) totals; also computes dis = rsqrt(deg+1).
__global__ __launch_bounds__(256) void scan_partial(const int* __restrict__ cnt,
        int* __restrict__ bsum, float* __restrict__ dis, int n) {
    __shared__ int red[256];
    int b = blockIdx.x, tid = threadIdx.x;
    int base = b * 1024 + tid * 4;
    int4 v = make_int4(0, 0, 0, 0);
    if (base + 4 <= n) {
        v = *reinterpret_cast<const int4*>(cnt + base);
    } else {
        if (base + 0 < n) v.x = cnt[base + 0];
        if (base + 1 < n) v.y = cnt[base + 1];
        if (base + 2 < n) v.z = cnt[base + 2];
    }
    if (base + 0 < n) dis[base + 0] = rsqrtf((float)(v.x + 1));
    if (base + 1 < n) dis[base + 1] = rsqrtf((float)(v.y + 1));
    if (base + 2 < n) dis[base + 2] = rsqrtf((float)(v.z + 1));
    if (base + 3 < n) dis[base + 3] = rsqrtf((float)(v.w + 1));
    red[tid] = v.x + v.y + v.z + v.w;
    __syncthreads();
    for (int d = 128; d > 0; d >>= 1) {
        if (tid < d) red[tid] += red[tid + d];
        __syncthreads();
    }
    if (tid == 0) bsum[b] = red[0];
}

// Pass 2: wave 0 redundantly scans block sums for this block's offset, then
// block-local exclusive scan + offset -> row_ptr.
__global__ __launch_bounds__(256) void scan_final(const int* __restrict__ cnt,
        const int* __restrict__ bsum, int* __restrict__ row_ptr, int nb, int n) {
    __shared__ int red[256];
    __shared__ int sh_boff;
    int b = blockIdx.x, tid = threadIdx.x;
    if (tid < 64) {
        int s = (tid < nb) ? bsum[tid] : 0;
        int v = s;
        for (int d = 1; d < 64; d <<= 1) {
            int t = __shfl_up(v, d);
            if (tid >= d) v += t;
        }
        if (tid == b) sh_boff = v - s;                 // exclusive offset of this block
        if (b == 0 && tid == 63) row_ptr[n] = v;       // grand total
    }
    int base = b * 1024 + tid * 4;
    int4 v = make_int4(0, 0, 0, 0);
    if (base + 4 <= n) {
        v = *reinterpret_cast<const int4*>(cnt + base);
    } else {
        if (base + 0 < n) v.x = cnt[base + 0];
        if (base + 1 < n) v.y = cnt[base + 1];
        if (base + 2 < n) v.z = cnt[base + 2];
    }
    int s = v.x + v.y + v.z + v.w;
    red[tid] = s;
    __syncthreads();
    for (int d = 1; d < 256; d <<= 1) {
        int t = (tid >= d) ? red[tid - d] : 0;
        __syncthreads();
        red[tid] += t;
        __syncthreads();
    }
    int off = sh_boff + red[tid] - s;
    if (base + 0 < n) { row_ptr[base + 0] = off; off += v.x; }
    if (base + 1 < n) { row_ptr[base + 1] = off; off += v.y; }
    if (base + 2 < n) { row_ptr[base + 2] = off; off += v.z; }
    if (base + 3 < n) { row_ptr[base + 3] = off; }
}

__global__ void fill_kernel(const int* __restrict__ ei, int E,
                            const int* __restrict__ row_ptr, int* __restrict__ fillc,
                            const float* __restrict__ dis, int2e* __restrict__ esort) {
    int i = blockIdx.x * blockDim.x + threadIdx.x;
    int stride = gridDim.x * blockDim.x;
    for (int e = i; e < E; e += stride) {
        int s = ei[e];
        int d = ei[E + e];
        int pos = row_ptr[d] + atomicAdd(&fillc[d], 1);
        float nm = dis[s] * dis[d];
        int2e pkt;
        pkt.x = s;
        pkt.y = __float_as_int(nm);
        esort[pos] = pkt;
    }
}

// One-time: Wt[c][k] = bf16(W[k][c]) for both weight matrices (blockIdx picks).
__global__ __launch_bounds__(256) void wt_kernel(const float* __restrict__ Wa,
        const float* __restrict__ Wb, u16* __restrict__ Wta, u16* __restrict__ Wtb) {
    const float* W = blockIdx.x ? Wb : Wa;
    u16* Wt = blockIdx.x ? Wtb : Wta;
    int tid = threadIdx.x;
    for (int i = 0; i < 64; ++i) {
        int idx = tid + i * 256;          // 16384 = 128*128
        int k = idx >> 7, c = idx & 127;
        Wt[c * 128 + k] = bf16_1(W[idx]); // read coalesced, write scattered (once)
    }
}

// out u16[n][128] = bf16( A[n][128] @ W ),  W given as Wt bf16 [col][k].
// MFMA 16x16x32 bf16. Block = 4 waves, 64 rows; wave owns 32 cols (2 n-tiles).
// TA: float (layer-1 x) or u16 (bf16 feature rows).
template <typename TA>
__global__ __launch_bounds__(256) void gemm_mfma(const TA* __restrict__ A,
        const u16* __restrict__ Wt, u16* __restrict__ out, int n) {
    constexpr int LDA = 136;                 // 128 + 8 pad (bf16) -> 2-way LDS only
    __shared__ u16 as[64 * LDA];
    int tid = threadIdx.x;
    int wave = tid >> 6, lane = tid & 63;
    int row0 = blockIdx.x * 64;
    int l16 = lane & 15;
    int krow = (lane >> 4) * 8;              // k-octet within 32-wide K block

    // ---- stage A rows (convert to bf16 if needed) ----
    if constexpr (sizeof(TA) == 4) {
#pragma unroll
        for (int i = 0; i < 8; ++i) {
            int idx = tid + i * 256;         // 2048 quads of 4 f32
            int r = idx >> 5;
            int q = (idx & 31) * 4;
            float4e v = {0.f, 0.f, 0.f, 0.f};
            if (row0 + r < n)
                v = *reinterpret_cast<const float4e*>((const float*)A + (size_t)(row0 + r) * 128 + q);
            uint2e p;
            p.x = pack_bf2(v.x, v.y);
            p.y = pack_bf2(v.z, v.w);
            *reinterpret_cast<uint2e*>(&as[r * LDA + q]) = p;
        }
    } else {
#pragma unroll
        for (int i = 0; i < 4; ++i) {
            int idx = tid + i * 256;         // 1024 octs of 8 bf16
            int r = idx >> 4;
            int q = (idx & 15) * 8;
            uint4e v = {0u, 0u, 0u, 0u};
            if (row0 + r < n)
                v = *reinterpret_cast<const uint4e*>((const u16*)A + (size_t)(row0 + r) * 128 + q);
            *reinterpret_cast<uint4e*>(&as[r * LDA + q]) = v;
        }
    }

    // ---- B fragments in registers: Wt[col][k], col = wave*32 + n2*16 + l16 ----
    bf16x8 b[2][4];
#pragma unroll
    for (int n2 = 0; n2 < 2; ++n2)
#pragma unroll
        for (int kb = 0; kb < 4; ++kb)
            b[n2][kb] = *reinterpret_cast<const bf16x8*>(
                Wt + (size_t)(wave * 32 + n2 * 16 + l16) * 128 + kb * 32 + krow);

    __syncthreads();

    f32x4 acc[4][2] = {};
#pragma unroll
    for (int m = 0; m < 4; ++m) {
#pragma unroll
        for (int kb = 0; kb < 4; ++kb) {
            bf16x8 a = *reinterpret_cast<const bf16x8*>(
                &as[(m * 16 + l16) * LDA + kb * 32 + krow]);
#pragma unroll
            for (int n2 = 0; n2 < 2; ++n2)
                acc[m][n2] = __builtin_amdgcn_mfma_f32_16x16x32_bf16(a, b[n2][kb], acc[m][n2], 0, 0, 0);
        }
    }

    // ---- write C: col = lane&15 (+tile), row = (lane>>4)*4 + reg (+tile) ----
#pragma unroll
    for (int m = 0; m < 4; ++m) {
        int rbase = row0 + m * 16 + (lane >> 4) * 4;
#pragma unroll
        for (int n2 = 0; n2 < 2; ++n2) {
            int col = wave * 32 + n2 * 16 + l16;
#pragma unroll
            for (int r = 0; r < 4; ++r) {
                int row = rbase + r;
                if (row < n) out[(size_t)row * 128 + col] = bf16_1(acc[m][n2][r]);
            }
        }
    }
}

// Shared gather core: 8 outstanding gathers per wave (latency hiding).
__device__ __forceinline__ void gather_accum(const uint* __restrict__ xw,
        const int2e* __restrict__ esort, const float* __restrict__ dis,
        int v, int lane, int beg, int end, float& ax, float& ay) {
    int e = beg;
    for (; e + 7 < end; e += 8) {
        int2e ed[8];
        uint vv[8];
#pragma unroll
        for (int j = 0; j < 8; ++j) ed[j] = esort[e + j];
#pragma unroll
        for (int j = 0; j < 8; ++j) vv[j] = xw[(size_t)ed[j].x * 64 + lane];
#pragma unroll
        for (int j = 0; j < 8; ++j) {
            float w = __int_as_float(ed[j].y);
            ax += w * bf_lo(vv[j]);
            ay += w * bf_hi(vv[j]);
        }
    }
    for (; e + 1 < end; e += 2) {
        int2e e0 = esort[e];
        int2e e1 = esort[e + 1];
        uint v0 = xw[(size_t)e0.x * 64 + lane];
        uint v1 = xw[(size_t)e1.x * 64 + lane];
        float w0 = __int_as_float(e0.y), w1 = __int_as_float(e1.y);
        ax += w0 * bf_lo(v0); ay += w0 * bf_hi(v0);
        ax += w1 * bf_lo(v1); ay += w1 * bf_hi(v1);
    }
    if (e < end) {
        int2e e0 = esort[e];
        uint v0 = xw[(size_t)e0.x * 64 + lane];
        float w0 = __int_as_float(e0.y);
        ax += w0 * bf_lo(v0); ay += w0 * bf_hi(v0);
    }
    float dv = dis[v];
    float wv = dv * dv;                            // self-loop norm
    uint vs = xw[(size_t)v * 64 + lane];
    ax += wv * bf_lo(vs); ay += wv * bf_hi(vs);
}

// CSR aggregation -> packed bf16. MODE: 1 = +bias, 2 = +bias+relu.
template <int MODE>
__global__ __launch_bounds__(256) void agg_kernel(const uint* __restrict__ xw,
        const int* __restrict__ row_ptr, const int2e* __restrict__ esort,
        const float* __restrict__ dis, const float* __restrict__ bias,
        uint* __restrict__ out, int n) {
    int v = (int)((blockIdx.x * blockDim.x + threadIdx.x) >> 6);
    int lane = threadIdx.x & 63;
    if (v >= n) return;
    float ax = 0.f, ay = 0.f;
    gather_accum(xw, esort, dis, v, lane, row_ptr[v], row_ptr[v + 1], ax, ay);
    ax += bias[lane * 2];
    ay += bias[lane * 2 + 1];
    if (MODE == 2) { ax = fmaxf(ax, 0.f); ay = fmaxf(ay, 0.f); }
    out[(size_t)v * 64 + lane] = pack_bf2(ax, ay);
}

// Final layer fused: h = Agg(h2); out = log_softmax(h @ W3 + b3).
__global__ __launch_bounds__(256) void agg_out_kernel(const uint* __restrict__ xw,
        const int* __restrict__ row_ptr, const int2e* __restrict__ esort,
        const float* __restrict__ dis, const float* __restrict__ W3,
        const float* __restrict__ b3, float* __restrict__ out, int n) {
    int v = (int)((blockIdx.x * blockDim.x + threadIdx.x) >> 6);
    int lane = threadIdx.x & 63;
    if (v >= n) return;
    float ax = 0.f, ay = 0.f;
    gather_accum(xw, esort, dis, v, lane, row_ptr[v], row_ptr[v + 1], ax, ay);
    const float* w0 = W3 + (size_t)lane * 20;   // this lane's 2 rows of W3
    float p[10];
#pragma unroll
    for (int c = 0; c < 10; ++c) p[c] = ax * w0[c] + ay * w0[10 + c];
#pragma unroll
    for (int c = 0; c < 10; ++c) {
#pragma unroll
        for (int d = 1; d < 64; d <<= 1) p[c] += __shfl_xor(p[c], d);
    }
#pragma unroll
    for (int c = 0; c < 10; ++c) p[c] += b3[c];
    float m = p[0];
#pragma unroll
    for (int c = 1; c < 10; ++c) m = fmaxf(m, p[c]);
    float ssum = 0.f;
#pragma unroll
    for (int c = 0; c < 10; ++c) ssum += __expf(p[c] - m);
    float ls = __logf(ssum);
    if (lane < 10) out[(size_t)v * 10 + lane] = p[lane] - m - ls;
}

extern "C" void kernel_launch(void* const* d_in, const int* in_sizes, int n_in,
                              void* d_out, int out_size, void* d_ws, size_t ws_size,
                              hipStream_t stream) {
    const float* x  = (const float*)d_in[0];
    const int*   ei = (const int*)d_in[1];   // [2][E] int32
    const float* W1 = (const float*)d_in[2];
    const float* b1 = (const float*)d_in[3];
    const float* W2 = (const float*)d_in[4];
    const float* b2 = (const float*)d_in[5];
    const float* W3 = (const float*)d_in[6];
    const float* b3 = (const float*)d_in[7];
    int N = in_sizes[0] / 128;
    int E = in_sizes[1] / 2;
    int NB = (N + 1023) / 1024;   // 49 for N=50000 (must be <= 64)

    char* ws = (char*)d_ws;
    size_t off = 0;
    auto alloc = [&](size_t bytes) -> char* {
        char* p = ws + off;
        off = (off + bytes + 255) & ~(size_t)255;
        return p;
    };
    int*   cnt     = (int*)alloc((size_t)N * 4);
    int*   fillc   = (int*)alloc((size_t)N * 4);
    int*   row_ptr = (int*)alloc(((size_t)N + 1) * 4);
    float* dis     = (float*)alloc((size_t)N * 4);
    int*   bsum    = (int*)alloc(64 * 4);
    u16*   Wt1     = (u16*)alloc(128 * 128 * 2);
    u16*   Wt2     = (u16*)alloc(128 * 128 * 2);
    int2e* esort   = (int2e*)alloc((size_t)E * 8);
    uint*  bufA    = (uint*)alloc((size_t)N * 64 * 4);   // bf16x2 packed [N][64]
    uint*  bufB    = (uint*)alloc((size_t)N * 64 * 4);   // bf16x2 packed [N][64]

    (void)hipMemsetAsync(cnt, 0, (size_t)N * 4, stream);
    (void)hipMemsetAsync(fillc, 0, (size_t)N * 4, stream);

    // --- graph preprocessing (shared by all 3 layers) + weight transposes ---
    count_kernel<<<2048, 256, 0, stream>>>(ei, E, cnt);
    wt_kernel<<<2, 256, 0, stream>>>(W1, W2, Wt1, Wt2);
    scan_partial<<<NB, 256, 0, stream>>>(cnt, bsum, dis, N);
    scan_final<<<NB, 256, 0, stream>>>(cnt, bsum, row_ptr, NB, N);
    fill_kernel<<<2048, 256, 0, stream>>>(ei, E, row_ptr, fillc, dis, esort);

    int gemm_grid = (N + 63) / 64;
    // --- layer 1: relu(Agg(x@W1) + b1) ---
    gemm_mfma<float><<<gemm_grid, 256, 0, stream>>>(x, Wt1, (u16*)bufA, N);
    agg_kernel<2><<<(N + 3) / 4, 256, 0, stream>>>(bufA, row_ptr, esort, dis, b1, bufB, N);
    // --- layer 2: Agg(h1@W2) + b2 ---
    gemm_mfma<u16><<<gemm_grid, 256, 0, stream>>>((const u16*)bufB, Wt2, (u16*)bufA, N);
    agg_kernel<1><<<(N + 3) / 4, 256, 0, stream>>>(bufA, row_ptr, esort, dis, b2, bufB, N);
    // --- layer 3 fused: log_softmax(Agg(h2) @ W3 + b3) ---
    agg_out_kernel<<<(N + 3) / 4, 256, 0, stream>>>(bufB, row_ptr, esort, dis, W3, b3,
                                                    (float*)d_out, N);
}